// Round 10
// baseline (107.032 us; speedup 1.0000x reference)
//
#include <hip/hip_runtime.h>
#include <math.h>

#define BLOCK 64
#define BATCH 16384
#define EPB 8      // elements per block: 8 lanes per element
#define EP 9       // element-dim stride for small per-element LDS arrays
#define NDOF 7
#define ACTION_RANGE 50.0f
#define MAX_VEL 20.0f
#define HSTEP 0.1f

__device__ __forceinline__ void mat3_mul(float* C, const float* A, const float* B) {
#pragma unroll
  for (int r = 0; r < 3; r++) {
#pragma unroll
    for (int c = 0; c < 3; c++) {
      C[r*3+c] = A[r*3+0]*B[0*3+c] + A[r*3+1]*B[1*3+c] + A[r*3+2]*B[2*3+c];
    }
  }
}

__device__ __forceinline__ void mat3_vec(float* y, const float* A, const float* x) {
#pragma unroll
  for (int r = 0; r < 3; r++)
    y[r] = A[r*3+0]*x[0] + A[r*3+1]*x[1] + A[r*3+2]*x[2];
}

__device__ __forceinline__ void mat3T_vec(float* y, const float* A, const float* x) {
#pragma unroll
  for (int r = 0; r < 3; r++)
    y[r] = A[0*3+r]*x[0] + A[1*3+r]*x[1] + A[2*3+r]*x[2];
}

__device__ __forceinline__ void cross3(float* y, const float* a, const float* b) {
  y[0] = a[1]*b[2] - a[2]*b[1];
  y[1] = a[2]*b[0] - a[0]*b[2];
  y[2] = a[0]*b[1] - a[1]*b[0];
}

// R = I + s*W + (1-c)*W^2 ; p = (th*I + (1-c)*W + (th-s)*W^2) v
__device__ __forceinline__ void exp_se3(const float* A6, float th, float* R, float* p) {
  float w0 = A6[0], w1 = A6[1], w2 = A6[2];
  float s = __sinf(th);
  float c = __cosf(th);
  float omc = 1.0f - c, tms = th - s;
  float W[9]  = {0.f, -w2, w1,  w2, 0.f, -w0,  -w1, w0, 0.f};
  float W2[9];
  mat3_mul(W2, W, W);
#pragma unroll
  for (int k = 0; k < 9; k++) R[k] = s*W[k] + omc*W2[k];
  R[0] += 1.f; R[4] += 1.f; R[8] += 1.f;
  float G[9];
#pragma unroll
  for (int k = 0; k < 9; k++) G[k] = omc*W[k] + tms*W2[k];
  G[0] += th; G[4] += th; G[8] += th;
  mat3_vec(p, G, A6 + 3);
}

// python-style mod: a - floor(a/y)*y  (result in [0,y))
__device__ __forceinline__ float wrap_pi(float x) {
  const float PI_F   = 3.14159265358979323846f;
  const float TWO_PI = 6.28318530717958647692f;
  float a = x + PI_F;
  float r = a - floorf(a * (1.0f / TWO_PI)) * TWO_PI;
  return r - PI_F;
}

// R10: same role layout as R9 (8 lanes/element; lanes 0-6 = mass columns,
// lane 7 = V & Vd; fused fwd+bwd sweep). Change: per-element LDS records are
// contiguous + 16B-aligned, accessed as float4 -> ds_read_b128/ds_write_b128.
// R9 spent ~234 ds_read_b32/stage on the field-major sRB; e-major [e][i][20]
// records give 5xb128 per joint, broadcast within the 8-lane group, and the
// 140-word e-stride maps the 8 groups onto disjoint bank quads (12e mod 32
// covers all 32 banks once) -> conflict-free.
__global__ __launch_bounds__(BLOCK, 2) void arm_rk4_kernel(
    const float* __restrict__ g_state, const float* __restrict__ g_action,
    const float* __restrict__ g_M, const float* __restrict__ g_A,
    const float* __restrict__ g_G, const float* __restrict__ g_grav,
    float* __restrict__ g_out_state, float* __restrict__ g_out_ee)
{
  __shared__ float sMR[8][9];
  __shared__ float sMp[8][3];
  __shared__ float sIR[7][9];
  __shared__ float sIp[7][3];
  __shared__ __align__(16) float sA[7][8];   // padded row: 2xfloat4
  __shared__ __align__(16) float sG[7][4];   // 1xfloat4
  __shared__ float sg[3];
  __shared__ __align__(16) float sRB[EPB*7*20]; // [e][joint][20]: R[9],B[9],pad2
  __shared__ __align__(16) float sQh[EPB*7*8];  // [e][joint][8]: Vd w,v + pad2
  __shared__ float tauL[NDOF*EP];
  __shared__ float qaccL[NDOF*EP];
  __shared__ float qfL[NDOF*EP];
  __shared__ float MllL[28*EP];

  const int tid  = threadIdx.x;
  const int e    = tid >> 3;      // element slot 0..7
  const int r    = tid & 7;       // role 0..7
  const int base = tid & 0x38;    // first lane of this element group
  const int b    = blockIdx.x * EPB + e;

  if (tid < 8) {
    const float* Mi = g_M + tid*16;
    float a1[3] = {Mi[0], Mi[4], Mi[8]};
    float a2[3] = {Mi[1], Mi[5], Mi[9]};
    float p[3]  = {Mi[3], Mi[7], Mi[11]};
    float n1 = sqrtf(a1[0]*a1[0] + a1[1]*a1[1] + a1[2]*a1[2]);
    float b1[3] = {a1[0]/n1, a1[1]/n1, a1[2]/n1};
    float d = a2[0]*b1[0] + a2[1]*b1[1] + a2[2]*b1[2];
    float a2o[3] = {a2[0]-d*b1[0], a2[1]-d*b1[1], a2[2]-d*b1[2]};
    float n2 = sqrtf(a2o[0]*a2o[0] + a2o[1]*a2o[1] + a2o[2]*a2o[2]);
    float b2[3] = {a2o[0]/n2, a2o[1]/n2, a2o[2]/n2};
    float b3[3];
    cross3(b3, b1, b2);
    float R[9] = {b1[0], b2[0], b3[0],  b1[1], b2[1], b3[1],  b1[2], b2[2], b3[2]};
#pragma unroll
    for (int k = 0; k < 9; k++) sMR[tid][k] = R[k];
    sMp[tid][0] = p[0]; sMp[tid][1] = p[1]; sMp[tid][2] = p[2];
    if (tid < 7) {
#pragma unroll
      for (int rr = 0; rr < 3; rr++)
#pragma unroll
        for (int cc = 0; cc < 3; cc++) sIR[tid][rr*3+cc] = R[cc*3+rr];
#pragma unroll
      for (int rr = 0; rr < 3; rr++)
        sIp[tid][rr] = -(R[0*3+rr]*p[0] + R[1*3+rr]*p[1] + R[2*3+rr]*p[2]);
      const float* Ar = g_A + tid*6;
      float nw = sqrtf(Ar[0]*Ar[0] + Ar[1]*Ar[1] + Ar[2]*Ar[2]);
      sA[tid][0] = Ar[0]/nw; sA[tid][1] = Ar[1]/nw; sA[tid][2] = Ar[2]/nw;
      sA[tid][3] = Ar[3];    sA[tid][4] = Ar[4];    sA[tid][5] = Ar[5];
      sA[tid][6] = 0.f;      sA[tid][7] = 0.f;
      sG[tid][0] = fabsf(g_G[tid*4+0]);
      sG[tid][1] = fabsf(g_G[tid*4+1]);
      sG[tid][2] = fabsf(g_G[tid*4+2]);
      sG[tid][3] = fabsf(g_G[tid*4+3]);
    }
  }
  if (tid == 0) { sg[0] = g_grav[0]; sg[1] = g_grav[1]; sg[2] = g_grav[2]; }

  float q0 = 0.f, dq0 = 0.f, qs = 0.f, dqs = 0.f;
  float accq = 0.f, accd = 0.f;
  if (r < NDOF) {
    q0  = g_state[b*14 + r];
    dq0 = g_state[b*14 + 7 + r];
    float tau = g_action[b*7 + r] * ACTION_RANGE;
    qs = q0; dqs = dq0;
    tauL[r*EP + e] = tau;
  }
  __syncthreads();

  float4* const sRB4 = (float4*)sRB;
  float4* const sQh4 = (float4*)sQh;

#pragma unroll 1
  for (int st = 0; st < 4; st++) {
    float bias_reg[NDOF];   // valid on lane r==7

    // ---- (A) adjoint of joint r, lanes r<7: 5x ds_write_b128 ----
    if (r < NDOF) {
      float Ai[6];
#pragma unroll
      for (int k = 0; k < 6; k++) Ai[k] = sA[r][k];
      float Re[9], pe[3];
      exp_se3(Ai, -qs, Re, pe);
      float IRl[9];
#pragma unroll
      for (int k = 0; k < 9; k++) IRl[k] = sIR[r][k];
      float Tr9[9];
      mat3_mul(Tr9, Re, IRl);
      float Ipl[3] = {sIp[r][0], sIp[r][1], sIp[r][2]};
      float Tp[3];
      mat3_vec(Tp, Re, Ipl);
      Tp[0] += pe[0]; Tp[1] += pe[1]; Tp[2] += pe[2];
      float Bm[9];
#pragma unroll
      for (int c = 0; c < 3; c++) {
        Bm[0*3+c] = -Tp[2]*Tr9[1*3+c] + Tp[1]*Tr9[2*3+c];
        Bm[1*3+c] =  Tp[2]*Tr9[0*3+c] - Tp[0]*Tr9[2*3+c];
        Bm[2*3+c] = -Tp[1]*Tr9[0*3+c] + Tp[0]*Tr9[1*3+c];
      }
      float4* dst = sRB4 + (size_t)(e*7 + r)*5;
      dst[0] = make_float4(Tr9[0], Tr9[1], Tr9[2], Tr9[3]);
      dst[1] = make_float4(Tr9[4], Tr9[5], Tr9[6], Tr9[7]);
      dst[2] = make_float4(Tr9[8], Bm[0],  Bm[1],  Bm[2]);
      dst[3] = make_float4(Bm[3],  Bm[4],  Bm[5],  Bm[6]);
      dst[4] = make_float4(Bm[7],  Bm[8],  0.f,    0.f);
    }
    __syncthreads();

    // ---- (BC) fused forward+backward sweep, ALL 8 lanes ----
    {
      float Phw[NDOF][3], Phv[NDOF][3];
      float Pw[3] = {0.f, 0.f, 0.f}, Pv[3] = {0.f, 0.f, 0.f};
      float Qw[3] = {0.f, 0.f, 0.f}, Qv[3] = {0.f, 0.f, 0.f};
      if (r == 7) { Qv[0] = -sg[0]; Qv[1] = -sg[1]; Qv[2] = -sg[2]; }
#pragma unroll
      for (int i = 0; i < NDOF; i++) {
        const float4* src = sRB4 + (size_t)(e*7 + i)*5;
        float4 v0 = src[0], v1 = src[1], v2 = src[2], v3 = src[3], v4 = src[4];
        float R[9]  = {v0.x, v0.y, v0.z, v0.w, v1.x, v1.y, v1.z, v1.w, v2.x};
        float Bm[9] = {v2.y, v2.z, v2.w, v3.x, v3.y, v3.z, v3.w, v4.x, v4.y};
        float dqi = __shfl(dqs, base + i, 64);
        float Aw[3] = {sA[i][0], sA[i][1], sA[i][2]};
        float Av[3] = {sA[i][3], sA[i][4], sA[i][5]};
        // P
        float Tw[3], Tv[3], t2[3];
        mat3_vec(Tw, R,  Pw);
        mat3_vec(Tv, Bm, Pw);
        mat3_vec(t2, R,  Pv);
        float cA = (r == i) ? 1.f : ((r == 7) ? dqi : 0.f);
#pragma unroll
        for (int k = 0; k < 3; k++) {
          Pw[k] = Tw[k] + cA*Aw[k];
          Pv[k] = Tv[k] + t2[k] + cA*Av[k];
        }
        // Q = AdT*Q + dq_i * ad(P)A_i   (meaningful on lane 7 only)
        float Uw[3], Uv[3], u2[3];
        mat3_vec(Uw, R,  Qw);
        mat3_vec(Uv, Bm, Qw);
        mat3_vec(u2, R,  Qv);
        float c1[3], c2[3], c3[3];
        cross3(c1, Pw, Aw);
        cross3(c2, Pv, Aw);
        cross3(c3, Pw, Av);
        float c8 = (r == 7) ? dqi : 0.f;
#pragma unroll
        for (int k = 0; k < 3; k++) {
          Qw[k] = Uw[k] + c8*c1[k];
          Qv[k] = Uv[k] + u2[k] + c8*(c2[k]+c3[k]);
        }
        if (r == 7) {
          float4* qd = sQh4 + (size_t)(e*7 + i)*2;
          qd[0] = make_float4(Qw[0], Qw[1], Qw[2], Qv[0]);
          qd[1] = make_float4(Qv[1], Qv[2], 0.f, 0.f);
        }
#pragma unroll
        for (int k = 0; k < 3; k++) { Phw[i][k] = Pw[k]; Phv[i][k] = Pv[k]; }
      }
      // backward
      float Fw[3] = {0.f, 0.f, 0.f}, Fv[3] = {0.f, 0.f, 0.f};
#pragma unroll
      for (int i = NDOF-1; i >= 0; i--) {
        if (i < NDOF-1) {
          const float4* src = sRB4 + (size_t)(e*7 + i + 1)*5;
          float4 v0 = src[0], v1 = src[1], v2 = src[2], v3 = src[3], v4 = src[4];
          float R[9]  = {v0.x, v0.y, v0.z, v0.w, v1.x, v1.y, v1.z, v1.w, v2.x};
          float Bm[9] = {v2.y, v2.z, v2.w, v3.x, v3.y, v3.z, v3.w, v4.x, v4.y};
          float nw[3], nv[3], t[3];
          mat3T_vec(nw, R, Fw);
          mat3T_vec(t, Bm, Fv);
          nw[0] += t[0]; nw[1] += t[1]; nw[2] += t[2];
          mat3T_vec(nv, R, Fv);
          Fw[0] = nw[0]; Fw[1] = nw[1]; Fw[2] = nw[2];
          Fv[0] = nv[0]; Fv[1] = nv[1]; Fv[2] = nv[2];
        }
        float gx = sG[i][0], gy = sG[i][1], gz = sG[i][2], m_ = sG[i][3];
        float aw[3] = {gx*Phw[i][0], gy*Phw[i][1], gz*Phw[i][2]};
        float av[3] = {m_*Phv[i][0], m_*Phv[i][1], m_*Phv[i][2]};
        const float4* qd = sQh4 + (size_t)(e*7 + i)*2;
        float4 q0v = qd[0], q1v = qd[1];
        float GDw[3] = {gx*q0v.x, gy*q0v.y, gz*q0v.z};
        float GDv[3] = {m_*q0v.w, m_*q1v.x, m_*q1v.y};
        float x1[3], x2[3], x3[3];
        cross3(x1, Phw[i], aw);   // Vw x GVw  (lane-7 semantics)
        cross3(x2, Phv[i], av);   // Vv x GVv
        cross3(x3, Phw[i], av);   // Vw x GVv
        const bool l7 = (r == 7);
#pragma unroll
        for (int k = 0; k < 3; k++) {
          Fw[k] += l7 ? (GDw[k] + x1[k] + x2[k]) : aw[k];
          Fv[k] += l7 ? (GDv[k] + x3[k])         : av[k];
        }
        float val = Fw[0]*sA[i][0] + Fw[1]*sA[i][1] + Fw[2]*sA[i][2]
                  + Fv[0]*sA[i][3] + Fv[1]*sA[i][4] + Fv[2]*sA[i][5];
        if (r < NDOF && i >= r) MllL[(i*(i+1)/2 + r)*EP + e] = val;
        if (r == 7) bias_reg[i] = val;
      }
    }
    __syncthreads();

    // ---- (D) Cholesky solve, lane r==7 (reciprocal-cached) ----
    if (r == 7) {
      float Lm[28], invd[NDOF];
#pragma unroll
      for (int idx = 0; idx < 28; idx++) Lm[idx] = MllL[idx*EP + e];
      float y[NDOF];
#pragma unroll
      for (int i = 0; i < NDOF; i++) y[i] = tauL[i*EP + e] - bias_reg[i];
#pragma unroll
      for (int k = 0; k < NDOF; k++) {
        float d = Lm[k*(k+1)/2 + k];
#pragma unroll
        for (int m2 = 0; m2 < k; m2++) { float l = Lm[k*(k+1)/2 + m2]; d -= l*l; }
        d = sqrtf(d);
        Lm[k*(k+1)/2 + k] = d;
        float inv = 1.0f / d;
        invd[k] = inv;
#pragma unroll
        for (int i = k+1; i < NDOF; i++) {
          float s = Lm[i*(i+1)/2 + k];
#pragma unroll
          for (int m2 = 0; m2 < k; m2++) s -= Lm[i*(i+1)/2 + m2]*Lm[k*(k+1)/2 + m2];
          Lm[i*(i+1)/2 + k] = s * inv;
        }
      }
#pragma unroll
      for (int i = 0; i < NDOF; i++) {
        float s = y[i];
#pragma unroll
        for (int m2 = 0; m2 < i; m2++) s -= Lm[i*(i+1)/2 + m2]*y[m2];
        y[i] = s * invd[i];
      }
      float qac[NDOF];
#pragma unroll
      for (int i = NDOF-1; i >= 0; i--) {
        float s = y[i];
#pragma unroll
        for (int m2 = i+1; m2 < NDOF; m2++) s -= Lm[m2*(m2+1)/2 + i]*qac[m2];
        qac[i] = s * invd[i];
      }
#pragma unroll
      for (int i = 0; i < NDOF; i++) qaccL[i*EP + e] = qac[i];
    }
    __syncthreads();

    // ---- (E) RK4 stage update, lanes r<7 ----
    if (r < NDOF) {
      float a = qaccL[r*EP + e];
      float w = (st == 0 || st == 3) ? 1.0f : 2.0f;
      accq += w * dqs;
      accd += w * a;
      if (st < 3) {
        float c = (st == 2) ? HSTEP : 0.5f*HSTEP;
        qs  = q0  + c * dqs;
        dqs = dq0 + c * a;
      }
    }
  }

  const float h6 = HSTEP / 6.0f;
  if (r < NDOF) {
    float qf = wrap_pi(q0 + h6*accq);
    float v  = dq0 + h6*accd;
    float dqf = fminf(fmaxf(v, -MAX_VEL), MAX_VEL);
    qfL[r*EP + e] = qf;
    g_out_state[b*14 + r]     = qf;
    g_out_state[b*14 + 7 + r] = dqf;
  }
  __syncthreads();

  if (r == 7) {
    float Tr9[9] = {1,0,0, 0,1,0, 0,0,1};
    float Tp[3] = {0,0,0};
#pragma unroll
    for (int i = 0; i < NDOF; i++) {
      float MRl[9];
#pragma unroll
      for (int k = 0; k < 9; k++) MRl[k] = sMR[i][k];
      float Mpl[3] = {sMp[i][0], sMp[i][1], sMp[i][2]};
      float R1[9];
      mat3_mul(R1, Tr9, MRl);
      float p1[3];
      mat3_vec(p1, Tr9, Mpl);
      p1[0] += Tp[0]; p1[1] += Tp[1]; p1[2] += Tp[2];
      float Ai[6];
#pragma unroll
      for (int k = 0; k < 6; k++) Ai[k] = sA[i][k];
      float Re[9], pe[3];
      exp_se3(Ai, qfL[i*EP + e], Re, pe);
      mat3_mul(Tr9, R1, Re);
      mat3_vec(Tp, R1, pe);
      Tp[0] += p1[0]; Tp[1] += p1[1]; Tp[2] += p1[2];
    }
    float Mp7[3] = {sMp[7][0], sMp[7][1], sMp[7][2]};
    float pf[3];
    mat3_vec(pf, Tr9, Mp7);
    g_out_ee[b*2 + 0] = pf[0] + Tp[0];
    g_out_ee[b*2 + 1] = pf[1] + Tp[1];
  }
}

extern "C" void kernel_launch(void* const* d_in, const int* in_sizes, int n_in,
                              void* d_out, int out_size, void* d_ws, size_t ws_size,
                              hipStream_t stream) {
  const float* state  = (const float*)d_in[0];  // (16384,14)
  const float* action = (const float*)d_in[1];  // (16384,7)
  const float* M      = (const float*)d_in[2];  // (8,4,4)
  const float* A      = (const float*)d_in[3];  // (7,6)
  const float* G      = (const float*)d_in[4];  // (7,4)
  const float* grav   = (const float*)d_in[5];  // (3,)
  float* out_state = (float*)d_out;                       // (16384,14)
  float* out_ee    = (float*)d_out + (size_t)BATCH * 14;  // (16384,2)

  arm_rk4_kernel<<<BATCH / EPB, BLOCK, 0, stream>>>(
      state, action, M, A, G, grav, out_state, out_ee);
}

// Round 11
// 106.140 us; speedup vs baseline: 1.0084x; 1.0084x over previous
//
#include <hip/hip_runtime.h>
#include <math.h>

#define BLOCK 64
#define BATCH 16384
#define EPB 8      // elements per block: 8 lanes per element
#define EP 9       // element-dim stride for MllL
#define NDOF 7
#define ACTION_RANGE 50.0f
#define MAX_VEL 20.0f
#define HSTEP 0.1f

typedef float v2f __attribute__((ext_vector_type(2)));

__device__ __forceinline__ void mat3_mul(float* C, const float* A, const float* B) {
#pragma unroll
  for (int r = 0; r < 3; r++) {
#pragma unroll
    for (int c = 0; c < 3; c++) {
      C[r*3+c] = A[r*3+0]*B[0*3+c] + A[r*3+1]*B[1*3+c] + A[r*3+2]*B[2*3+c];
    }
  }
}

__device__ __forceinline__ void mat3_vec(float* y, const float* A, const float* x) {
#pragma unroll
  for (int r = 0; r < 3; r++)
    y[r] = A[r*3+0]*x[0] + A[r*3+1]*x[1] + A[r*3+2]*x[2];
}

__device__ __forceinline__ void cross3(float* y, const float* a, const float* b) {
  y[0] = a[1]*b[2] - a[2]*b[1];
  y[1] = a[2]*b[0] - a[0]*b[2];
  y[2] = a[0]*b[1] - a[1]*b[0];
}

// R = I + s*W + (1-c)*W^2 ; p = (th*I + (1-c)*W + (th-s)*W^2) v
__device__ __forceinline__ void exp_se3(const float* A6, float th, float* R, float* p) {
  float w0 = A6[0], w1 = A6[1], w2 = A6[2];
  float s = __sinf(th);
  float c = __cosf(th);
  float omc = 1.0f - c, tms = th - s;
  float W[9]  = {0.f, -w2, w1,  w2, 0.f, -w0,  -w1, w0, 0.f};
  float W2[9];
  mat3_mul(W2, W, W);
#pragma unroll
  for (int k = 0; k < 9; k++) R[k] = s*W[k] + omc*W2[k];
  R[0] += 1.f; R[4] += 1.f; R[8] += 1.f;
  float G[9];
#pragma unroll
  for (int k = 0; k < 9; k++) G[k] = omc*W[k] + tms*W2[k];
  G[0] += th; G[4] += th; G[8] += th;
  mat3_vec(p, G, A6 + 3);
}

// python-style mod
__device__ __forceinline__ float wrap_pi(float x) {
  const float PI_F   = 3.14159265358979323846f;
  const float TWO_PI = 6.28318530717958647692f;
  float a = x + PI_F;
  float r = a - floorf(a * (1.0f / TWO_PI)) * TWO_PI;
  return r - PI_F;
}

// R11 = R9 roles (8 lanes/el; r<7 mass cols, lane7 V&Vd) with:
//  (a) sRB as column-(row0,row1)-pairs + row2 scalars -> ds_read_b64 feeding
//      v_pk_fma_f32 directly (R10 lesson: no unpack movs allowed);
//  (b) tau/qacc/qf moved from LDS+barrier to __shfl (drops 2 barriers/stage
//      equivalents + LDS arrays).
__global__ __launch_bounds__(BLOCK, 2) void arm_rk4_kernel(
    const float* __restrict__ g_state, const float* __restrict__ g_action,
    const float* __restrict__ g_M, const float* __restrict__ g_A,
    const float* __restrict__ g_G, const float* __restrict__ g_grav,
    float* __restrict__ g_out_state, float* __restrict__ g_out_ee)
{
  __shared__ float sMR[8][9];
  __shared__ float sMp[8][3];
  __shared__ float sIR[7][9];
  __shared__ float sIp[7][3];
  // sA row: {w0,w1,v0,v1,w2,v2,0,0} -> w01 pair @0, v01 pair @2
  __shared__ __align__(16) float sA[7][8];
  __shared__ __align__(16) float sG[7][4];
  __shared__ float sg[3];
  // per (e,joint) record, 20 floats:
  // 0:(R00,R10) 2:(R01,R11) 4:(R02,R12) 6:(B00,B10) 8:(B01,B11) 10:(B02,B12)
  // 12..14: R2c  15..17: B2c  18,19: pad
  __shared__ __align__(16) float sRB[EPB*7*20];
  // per (e,joint) Vd record, 8 floats: 0:Qw01 2:Qv01 4:Qw2 5:Qv2 6,7 pad
  __shared__ __align__(16) float sQh[EPB*7*8];
  __shared__ float MllL[28*EP];

  const int tid  = threadIdx.x;
  const int e    = tid >> 3;
  const int r    = tid & 7;
  const int base = tid & 0x38;
  const int b    = blockIdx.x * EPB + e;

  if (tid < 8) {
    const float* Mi = g_M + tid*16;
    float a1[3] = {Mi[0], Mi[4], Mi[8]};
    float a2[3] = {Mi[1], Mi[5], Mi[9]};
    float p[3]  = {Mi[3], Mi[7], Mi[11]};
    float n1 = sqrtf(a1[0]*a1[0] + a1[1]*a1[1] + a1[2]*a1[2]);
    float b1[3] = {a1[0]/n1, a1[1]/n1, a1[2]/n1};
    float d = a2[0]*b1[0] + a2[1]*b1[1] + a2[2]*b1[2];
    float a2o[3] = {a2[0]-d*b1[0], a2[1]-d*b1[1], a2[2]-d*b1[2]};
    float n2 = sqrtf(a2o[0]*a2o[0] + a2o[1]*a2o[1] + a2o[2]*a2o[2]);
    float b2[3] = {a2o[0]/n2, a2o[1]/n2, a2o[2]/n2};
    float b3[3];
    cross3(b3, b1, b2);
    float R[9] = {b1[0], b2[0], b3[0],  b1[1], b2[1], b3[1],  b1[2], b2[2], b3[2]};
#pragma unroll
    for (int k = 0; k < 9; k++) sMR[tid][k] = R[k];
    sMp[tid][0] = p[0]; sMp[tid][1] = p[1]; sMp[tid][2] = p[2];
    if (tid < 7) {
#pragma unroll
      for (int rr = 0; rr < 3; rr++)
#pragma unroll
        for (int cc = 0; cc < 3; cc++) sIR[tid][rr*3+cc] = R[cc*3+rr];
#pragma unroll
      for (int rr = 0; rr < 3; rr++)
        sIp[tid][rr] = -(R[0*3+rr]*p[0] + R[1*3+rr]*p[1] + R[2*3+rr]*p[2]);
      const float* Ar = g_A + tid*6;
      float nw = sqrtf(Ar[0]*Ar[0] + Ar[1]*Ar[1] + Ar[2]*Ar[2]);
      sA[tid][0] = Ar[0]/nw;  // w0
      sA[tid][1] = Ar[1]/nw;  // w1
      sA[tid][2] = Ar[3];     // v0
      sA[tid][3] = Ar[4];     // v1
      sA[tid][4] = Ar[2]/nw;  // w2
      sA[tid][5] = Ar[5];     // v2
      sA[tid][6] = 0.f; sA[tid][7] = 0.f;
      sG[tid][0] = fabsf(g_G[tid*4+0]);
      sG[tid][1] = fabsf(g_G[tid*4+1]);
      sG[tid][2] = fabsf(g_G[tid*4+2]);
      sG[tid][3] = fabsf(g_G[tid*4+3]);
    }
  }
  if (tid == 0) { sg[0] = g_grav[0]; sg[1] = g_grav[1]; sg[2] = g_grav[2]; }

  float q0 = 0.f, dq0 = 0.f, tau = 0.f, qs = 0.f, dqs = 0.f;
  float accq = 0.f, accd = 0.f;
  if (r < NDOF) {
    q0  = g_state[b*14 + r];
    dq0 = g_state[b*14 + 7 + r];
    tau = g_action[b*7 + r] * ACTION_RANGE;
    qs = q0; dqs = dq0;
  }
  __syncthreads();

  // gather tau once (all lanes execute; lane 7 uses)
  float tsw[NDOF];
#pragma unroll
  for (int i = 0; i < NDOF; i++) tsw[i] = __shfl(tau, base + i, 64);

#pragma unroll 1
  for (int st = 0; st < 4; st++) {
    float bias_reg[NDOF];   // valid on lane r==7

    // ---- (A) adjoint of joint r, lanes r<7 ----
    if (r < NDOF) {
      float Ai[6] = {sA[r][0], sA[r][1], sA[r][4], sA[r][2], sA[r][3], sA[r][5]};
      float Re[9], pe[3];
      exp_se3(Ai, -qs, Re, pe);
      float IRl[9];
#pragma unroll
      for (int k = 0; k < 9; k++) IRl[k] = sIR[r][k];
      float Tr9[9];
      mat3_mul(Tr9, Re, IRl);
      float Ipl[3] = {sIp[r][0], sIp[r][1], sIp[r][2]};
      float Tp[3];
      mat3_vec(Tp, Re, Ipl);
      Tp[0] += pe[0]; Tp[1] += pe[1]; Tp[2] += pe[2];
      float Bm[9];
#pragma unroll
      for (int c = 0; c < 3; c++) {
        Bm[0*3+c] = -Tp[2]*Tr9[1*3+c] + Tp[1]*Tr9[2*3+c];
        Bm[1*3+c] =  Tp[2]*Tr9[0*3+c] - Tp[0]*Tr9[2*3+c];
        Bm[2*3+c] = -Tp[1]*Tr9[0*3+c] + Tp[0]*Tr9[1*3+c];
      }
      float* rec = &sRB[(e*7 + r)*20];
      *(v2f*)(rec+0)  = (v2f){Tr9[0], Tr9[3]};
      *(v2f*)(rec+2)  = (v2f){Tr9[1], Tr9[4]};
      *(v2f*)(rec+4)  = (v2f){Tr9[2], Tr9[5]};
      *(v2f*)(rec+6)  = (v2f){Bm[0],  Bm[3]};
      *(v2f*)(rec+8)  = (v2f){Bm[1],  Bm[4]};
      *(v2f*)(rec+10) = (v2f){Bm[2],  Bm[5]};
      rec[12] = Tr9[6]; rec[13] = Tr9[7]; rec[14] = Tr9[8];
      rec[15] = Bm[6];  rec[16] = Bm[7];  rec[17] = Bm[8];
    }
    __syncthreads();

    // ---- (BC) fused forward+backward sweep, ALL 8 lanes ----
    {
      v2f   Phw01[NDOF], Phv01[NDOF];
      float Phw2[NDOF],  Phv2[NDOF];
      v2f Pw01 = (v2f){0.f, 0.f}, Pv01 = (v2f){0.f, 0.f};
      float Pw2 = 0.f, Pv2 = 0.f;
      v2f Qw01 = (v2f){0.f, 0.f}, Qv01 = (v2f){0.f, 0.f};
      float Qw2 = 0.f, Qv2 = 0.f;
      if (r == 7) { Qv01 = (v2f){-sg[0], -sg[1]}; Qv2 = -sg[2]; }
#pragma unroll
      for (int i = 0; i < NDOF; i++) {
        const float* rec = &sRB[(e*7 + i)*20];
        v2f Rc0 = *(const v2f*)(rec+0), Rc1 = *(const v2f*)(rec+2), Rc2 = *(const v2f*)(rec+4);
        v2f Bc0 = *(const v2f*)(rec+6), Bc1 = *(const v2f*)(rec+8), Bc2 = *(const v2f*)(rec+10);
        float Rz0 = rec[12], Rz1 = rec[13], Rz2 = rec[14];
        float Bz0 = rec[15], Bz1 = rec[16], Bz2 = rec[17];
        float dqi = __shfl(dqs, base + i, 64);
        v2f Aw01 = *(const v2f*)&sA[i][0];  float Aw2 = sA[i][4];
        v2f Av01 = *(const v2f*)&sA[i][2];  float Av2 = sA[i][5];
        // ---- P propagation (packed) ----
        float pw0 = Pw01.x, pw1 = Pw01.y, pw2 = Pw2;
        float pv0 = Pv01.x, pv1 = Pv01.y, pv2 = Pv2;
        v2f Tw01 = Rc0*pw0 + Rc1*pw1 + Rc2*pw2;
        float Tw2 = Rz0*pw0 + Rz1*pw1 + Rz2*pw2;
        v2f Tv01 = Bc0*pw0 + Bc1*pw1 + Bc2*pw2 + Rc0*pv0 + Rc1*pv1 + Rc2*pv2;
        float Tv2 = Bz0*pw0 + Bz1*pw1 + Bz2*pw2 + Rz0*pv0 + Rz1*pv1 + Rz2*pv2;
        float cA = (r == i) ? 1.f : ((r == 7) ? dqi : 0.f);
        Pw01 = Tw01 + cA*Aw01;  Pw2 = Tw2 + cA*Aw2;
        Pv01 = Tv01 + cA*Av01;  Pv2 = Tv2 + cA*Av2;
        // ---- Q propagation (packed), Coriolis from own new P (lane 7) ----
        float qw0 = Qw01.x, qw1 = Qw01.y, qw2 = Qw2;
        float qv0 = Qv01.x, qv1 = Qv01.y, qv2 = Qv2;
        v2f Uw01 = Rc0*qw0 + Rc1*qw1 + Rc2*qw2;
        float Uw2 = Rz0*qw0 + Rz1*qw1 + Rz2*qw2;
        v2f Uv01 = Bc0*qw0 + Bc1*qw1 + Bc2*qw2 + Rc0*qv0 + Rc1*qv1 + Rc2*qv2;
        float Uv2 = Bz0*qw0 + Bz1*qw1 + Bz2*qw2 + Rz0*qv0 + Rz1*qv1 + Rz2*qv2;
        float nPw[3] = {Pw01.x, Pw01.y, Pw2};
        float nPv[3] = {Pv01.x, Pv01.y, Pv2};
        float Awس[3] = {Aw01.x, Aw01.y, Aw2};
        float Avس[3] = {Av01.x, Av01.y, Av2};
        float c1[3], c2[3], c3[3];
        cross3(c1, nPw, Awس);
        cross3(c2, nPv, Awس);
        cross3(c3, nPw, Avس);
        float c8 = (r == 7) ? dqi : 0.f;
        Qw01.x = Uw01.x + c8*c1[0];  Qw01.y = Uw01.y + c8*c1[1];  Qw2 = Uw2 + c8*c1[2];
        Qv01.x = Uv01.x + c8*(c2[0]+c3[0]);
        Qv01.y = Uv01.y + c8*(c2[1]+c3[1]);
        Qv2    = Uv2    + c8*(c2[2]+c3[2]);
        if (r == 7) {
          float* qrec = &sQh[(e*7 + i)*8];
          *(v2f*)(qrec+0) = Qw01;
          *(v2f*)(qrec+2) = Qv01;
          qrec[4] = Qw2;  qrec[5] = Qv2;
        }
        Phw01[i] = Pw01;  Phw2[i] = Pw2;
        Phv01[i] = Pv01;  Phv2[i] = Pv2;
      }
      // backward
      float Fw[3] = {0.f, 0.f, 0.f}, Fv[3] = {0.f, 0.f, 0.f};
#pragma unroll
      for (int i = NDOF-1; i >= 0; i--) {
        if (i < NDOF-1) {
          const float* rec = &sRB[(e*7 + i + 1)*20];
          v2f Rc0 = *(const v2f*)(rec+0), Rc1 = *(const v2f*)(rec+2), Rc2 = *(const v2f*)(rec+4);
          v2f Bc0 = *(const v2f*)(rec+6), Bc1 = *(const v2f*)(rec+8), Bc2 = *(const v2f*)(rec+10);
          float Rz0 = rec[12], Rz1 = rec[13], Rz2 = rec[14];
          float Bz0 = rec[15], Bz1 = rec[16], Bz2 = rec[17];
          // F = AdT^T F: nw = R^T Fw + B^T Fv ; nv = R^T Fv
          float nw0 = Rc0.x*Fw[0] + Rc0.y*Fw[1] + Rz0*Fw[2] + Bc0.x*Fv[0] + Bc0.y*Fv[1] + Bz0*Fv[2];
          float nw1 = Rc1.x*Fw[0] + Rc1.y*Fw[1] + Rz1*Fw[2] + Bc1.x*Fv[0] + Bc1.y*Fv[1] + Bz1*Fv[2];
          float nw2 = Rc2.x*Fw[0] + Rc2.y*Fw[1] + Rz2*Fw[2] + Bc2.x*Fv[0] + Bc2.y*Fv[1] + Bz2*Fv[2];
          float nv0 = Rc0.x*Fv[0] + Rc0.y*Fv[1] + Rz0*Fv[2];
          float nv1 = Rc1.x*Fv[0] + Rc1.y*Fv[1] + Rz1*Fv[2];
          float nv2 = Rc2.x*Fv[0] + Rc2.y*Fv[1] + Rz2*Fv[2];
          Fw[0] = nw0; Fw[1] = nw1; Fw[2] = nw2;
          Fv[0] = nv0; Fv[1] = nv1; Fv[2] = nv2;
        }
        float gx = sG[i][0], gy = sG[i][1], gz = sG[i][2], m_ = sG[i][3];
        float Pwc[3] = {Phw01[i].x, Phw01[i].y, Phw2[i]};
        float Pvc[3] = {Phv01[i].x, Phv01[i].y, Phv2[i]};
        float aw[3] = {gx*Pwc[0], gy*Pwc[1], gz*Pwc[2]};
        float av[3] = {m_*Pvc[0], m_*Pvc[1], m_*Pvc[2]};
        const float* qrec = &sQh[(e*7 + i)*8];
        v2f dq01 = *(const v2f*)(qrec+0);
        v2f dv01 = *(const v2f*)(qrec+2);
        float GDw[3] = {gx*dq01.x, gy*dq01.y, gz*qrec[4]};
        float GDv[3] = {m_*dv01.x, m_*dv01.y, m_*qrec[5]};
        float x1[3], x2[3], x3[3];
        cross3(x1, Pwc, aw);
        cross3(x2, Pvc, av);
        cross3(x3, Pwc, av);
        const bool l7 = (r == 7);
#pragma unroll
        for (int k = 0; k < 3; k++) {
          Fw[k] += l7 ? (GDw[k] + x1[k] + x2[k]) : aw[k];
          Fv[k] += l7 ? (GDv[k] + x3[k])         : av[k];
        }
        float val = Fw[0]*sA[i][0] + Fw[1]*sA[i][1] + Fw[2]*sA[i][4]
                  + Fv[0]*sA[i][2] + Fv[1]*sA[i][3] + Fv[2]*sA[i][5];
        if (r < NDOF && i >= r) MllL[(i*(i+1)/2 + r)*EP + e] = val;
        if (r == 7) bias_reg[i] = val;
      }
    }
    __syncthreads();

    // ---- (D) Cholesky solve, lane r==7 ----
    float qac[NDOF] = {0.f, 0.f, 0.f, 0.f, 0.f, 0.f, 0.f};
    if (r == 7) {
      float Lm[28], invd[NDOF];
#pragma unroll
      for (int idx = 0; idx < 28; idx++) Lm[idx] = MllL[idx*EP + e];
      float y[NDOF];
#pragma unroll
      for (int i = 0; i < NDOF; i++) y[i] = tsw[i] - bias_reg[i];
#pragma unroll
      for (int k = 0; k < NDOF; k++) {
        float d = Lm[k*(k+1)/2 + k];
#pragma unroll
        for (int m2 = 0; m2 < k; m2++) { float l = Lm[k*(k+1)/2 + m2]; d -= l*l; }
        d = sqrtf(d);
        float inv = 1.0f / d;
        invd[k] = inv;
#pragma unroll
        for (int i = k+1; i < NDOF; i++) {
          float s = Lm[i*(i+1)/2 + k];
#pragma unroll
          for (int m2 = 0; m2 < k; m2++) s -= Lm[i*(i+1)/2 + m2]*Lm[k*(k+1)/2 + m2];
          Lm[i*(i+1)/2 + k] = s * inv;
        }
      }
#pragma unroll
      for (int i = 0; i < NDOF; i++) {
        float s = y[i];
#pragma unroll
        for (int m2 = 0; m2 < i; m2++) s -= Lm[i*(i+1)/2 + m2]*y[m2];
        y[i] = s * invd[i];
      }
#pragma unroll
      for (int i = NDOF-1; i >= 0; i--) {
        float s = y[i];
#pragma unroll
        for (int m2 = i+1; m2 < NDOF; m2++) s -= Lm[m2*(m2+1)/2 + i]*qac[m2];
        qac[i] = s * invd[i];
      }
    }
    // broadcast qac from lane 7 (no barrier needed)
    float aq = 0.f;
#pragma unroll
    for (int i = 0; i < NDOF; i++) {
      float t = __shfl(qac[i], base + 7, 64);
      if (r == i) aq = t;
    }

    // ---- (E) RK4 stage update, lanes r<7 ----
    if (r < NDOF) {
      float w = (st == 0 || st == 3) ? 1.0f : 2.0f;
      accq += w * dqs;
      accd += w * aq;
      if (st < 3) {
        float c = (st == 2) ? HSTEP : 0.5f*HSTEP;
        qs  = q0  + c * dqs;
        dqs = dq0 + c * aq;
      }
    }
  }

  const float h6 = HSTEP / 6.0f;
  float qfv = wrap_pi(q0 + h6*accq);    // lane 7 computes garbage; unused
  if (r < NDOF) {
    float v  = dq0 + h6*accd;
    float dqf = fminf(fmaxf(v, -MAX_VEL), MAX_VEL);
    g_out_state[b*14 + r]     = qfv;
    g_out_state[b*14 + 7 + r] = dqf;
  }
  // gather qf for FK (all lanes execute shuffles)
  float fsw[NDOF];
#pragma unroll
  for (int i = 0; i < NDOF; i++) fsw[i] = __shfl(qfv, base + i, 64);

  if (r == 7) {
    float Tr9[9] = {1,0,0, 0,1,0, 0,0,1};
    float Tp[3] = {0,0,0};
#pragma unroll
    for (int i = 0; i < NDOF; i++) {
      float MRl[9];
#pragma unroll
      for (int k = 0; k < 9; k++) MRl[k] = sMR[i][k];
      float Mpl[3] = {sMp[i][0], sMp[i][1], sMp[i][2]};
      float R1[9];
      mat3_mul(R1, Tr9, MRl);
      float p1[3];
      mat3_vec(p1, Tr9, Mpl);
      p1[0] += Tp[0]; p1[1] += Tp[1]; p1[2] += Tp[2];
      float Ai[6] = {sA[i][0], sA[i][1], sA[i][4], sA[i][2], sA[i][3], sA[i][5]};
      float Re[9], pe[3];
      exp_se3(Ai, fsw[i], Re, pe);
      mat3_mul(Tr9, R1, Re);
      mat3_vec(Tp, R1, pe);
      Tp[0] += p1[0]; Tp[1] += p1[1]; Tp[2] += p1[2];
    }
    float Mp7[3] = {sMp[7][0], sMp[7][1], sMp[7][2]};
    float pf[3];
    mat3_vec(pf, Tr9, Mp7);
    g_out_ee[b*2 + 0] = pf[0] + Tp[0];
    g_out_ee[b*2 + 1] = pf[1] + Tp[1];
  }
}

extern "C" void kernel_launch(void* const* d_in, const int* in_sizes, int n_in,
                              void* d_out, int out_size, void* d_ws, size_t ws_size,
                              hipStream_t stream) {
  const float* state  = (const float*)d_in[0];  // (16384,14)
  const float* action = (const float*)d_in[1];  // (16384,7)
  const float* M      = (const float*)d_in[2];  // (8,4,4)
  const float* A      = (const float*)d_in[3];  // (7,6)
  const float* G      = (const float*)d_in[4];  // (7,4)
  const float* grav   = (const float*)d_in[5];  // (3,)
  float* out_state = (float*)d_out;                       // (16384,14)
  float* out_ee    = (float*)d_out + (size_t)BATCH * 14;  // (16384,2)

  arm_rk4_kernel<<<BATCH / EPB, BLOCK, 0, stream>>>(
      state, action, M, A, G, grav, out_state, out_ee);
}

// Round 12
// 104.666 us; speedup vs baseline: 1.0226x; 1.0141x over previous
//
#include <hip/hip_runtime.h>
#include <math.h>

#define BLOCK 64
#define BATCH 16384
#define EPB 8      // elements per block: 8 lanes per element
#define EP 9       // element-dim stride for per-element LDS arrays
#define NDOF 7
#define ACTION_RANGE 50.0f
#define MAX_VEL 20.0f
#define HSTEP 0.1f

typedef float v2f __attribute__((ext_vector_type(2)));

__device__ __forceinline__ void mat3_mul(float* C, const float* A, const float* B) {
#pragma unroll
  for (int r = 0; r < 3; r++) {
#pragma unroll
    for (int c = 0; c < 3; c++) {
      C[r*3+c] = A[r*3+0]*B[0*3+c] + A[r*3+1]*B[1*3+c] + A[r*3+2]*B[2*3+c];
    }
  }
}

__device__ __forceinline__ void mat3_vec(float* y, const float* A, const float* x) {
#pragma unroll
  for (int r = 0; r < 3; r++)
    y[r] = A[r*3+0]*x[0] + A[r*3+1]*x[1] + A[r*3+2]*x[2];
}

__device__ __forceinline__ void mat3T_vec(float* y, const float* A, const float* x) {
#pragma unroll
  for (int r = 0; r < 3; r++)
    y[r] = A[0*3+r]*x[0] + A[1*3+r]*x[1] + A[2*3+r]*x[2];
}

__device__ __forceinline__ void cross3(float* y, const float* a, const float* b) {
  y[0] = a[1]*b[2] - a[2]*b[1];
  y[1] = a[2]*b[0] - a[0]*b[2];
  y[2] = a[0]*b[1] - a[1]*b[0];
}

// R = I + s*W + (1-c)*W^2 ; p = (th*I + (1-c)*W + (th-s)*W^2) v
__device__ __forceinline__ void exp_se3(const float* A6, float th, float* R, float* p) {
  float w0 = A6[0], w1 = A6[1], w2 = A6[2];
  float s = __sinf(th);
  float c = __cosf(th);
  float omc = 1.0f - c, tms = th - s;
  float W[9]  = {0.f, -w2, w1,  w2, 0.f, -w0,  -w1, w0, 0.f};
  float W2[9];
  mat3_mul(W2, W, W);
#pragma unroll
  for (int k = 0; k < 9; k++) R[k] = s*W[k] + omc*W2[k];
  R[0] += 1.f; R[4] += 1.f; R[8] += 1.f;
  float G[9];
#pragma unroll
  for (int k = 0; k < 9; k++) G[k] = omc*W[k] + tms*W2[k];
  G[0] += th; G[4] += th; G[8] += th;
  mat3_vec(p, G, A6 + 3);
}

// python-style mod: a - floor(a/y)*y  (result in [0,y))
__device__ __forceinline__ float wrap_pi(float x) {
  const float PI_F   = 3.14159265358979323846f;
  const float TWO_PI = 6.28318530717958647692f;
  float a = x + PI_F;
  float r = a - floorf(a * (1.0f / TWO_PI)) * TWO_PI;
  return r - PI_F;
}

// R12 = exact R9 (best: 45.5us) with ONE change: the BC forward sweep carries
// the column chain (P) and Vd chain (Q) packed as float2 (.x=P, .y=Q) so the
// 54 propagation FMAs/joint become 27 v_pk_fma_f32 (CDNA full-rate dual f32).
// Injections stay scalar; .x history in regs, .y history -> sQh (lane 7), as
// in R9. R10/R11 lesson: only accept vectorization with zero unpack overhead —
// here both halves are real independent chains consumed in packed form.
__global__ __launch_bounds__(BLOCK, 2) void arm_rk4_kernel(
    const float* __restrict__ g_state, const float* __restrict__ g_action,
    const float* __restrict__ g_M, const float* __restrict__ g_A,
    const float* __restrict__ g_G, const float* __restrict__ g_grav,
    float* __restrict__ g_out_state, float* __restrict__ g_out_ee)
{
  __shared__ float sMR[8][9];
  __shared__ float sMp[8][3];
  __shared__ float sIR[7][9];
  __shared__ float sIp[7][3];
  __shared__ float sA[7][6];
  __shared__ float sG[7][4];
  __shared__ float sg[3];
  __shared__ float sRB[7*18*EP];   // per joint: R[9], B[9]  (AdT = [[R,0],[B,R]])
  __shared__ float sQh[7*6*EP];    // per joint: Vd (lane-7 history)
  __shared__ float tauL[NDOF*EP];
  __shared__ float qaccL[NDOF*EP];
  __shared__ float qfL[NDOF*EP];
  __shared__ float MllL[28*EP];

  const int tid  = threadIdx.x;
  const int e    = tid >> 3;      // element slot 0..7
  const int r    = tid & 7;       // role 0..7
  const int base = tid & 0x38;    // first lane of this element group
  const int b    = blockIdx.x * EPB + e;

  if (tid < 8) {
    const float* Mi = g_M + tid*16;
    float a1[3] = {Mi[0], Mi[4], Mi[8]};
    float a2[3] = {Mi[1], Mi[5], Mi[9]};
    float p[3]  = {Mi[3], Mi[7], Mi[11]};
    float n1 = sqrtf(a1[0]*a1[0] + a1[1]*a1[1] + a1[2]*a1[2]);
    float b1[3] = {a1[0]/n1, a1[1]/n1, a1[2]/n1};
    float d = a2[0]*b1[0] + a2[1]*b1[1] + a2[2]*b1[2];
    float a2o[3] = {a2[0]-d*b1[0], a2[1]-d*b1[1], a2[2]-d*b1[2]};
    float n2 = sqrtf(a2o[0]*a2o[0] + a2o[1]*a2o[1] + a2o[2]*a2o[2]);
    float b2[3] = {a2o[0]/n2, a2o[1]/n2, a2o[2]/n2};
    float b3[3];
    cross3(b3, b1, b2);
    float R[9] = {b1[0], b2[0], b3[0],  b1[1], b2[1], b3[1],  b1[2], b2[2], b3[2]};
#pragma unroll
    for (int k = 0; k < 9; k++) sMR[tid][k] = R[k];
    sMp[tid][0] = p[0]; sMp[tid][1] = p[1]; sMp[tid][2] = p[2];
    if (tid < 7) {
#pragma unroll
      for (int rr = 0; rr < 3; rr++)
#pragma unroll
        for (int cc = 0; cc < 3; cc++) sIR[tid][rr*3+cc] = R[cc*3+rr];
#pragma unroll
      for (int rr = 0; rr < 3; rr++)
        sIp[tid][rr] = -(R[0*3+rr]*p[0] + R[1*3+rr]*p[1] + R[2*3+rr]*p[2]);
      const float* Ar = g_A + tid*6;
      float nw = sqrtf(Ar[0]*Ar[0] + Ar[1]*Ar[1] + Ar[2]*Ar[2]);
      sA[tid][0] = Ar[0]/nw; sA[tid][1] = Ar[1]/nw; sA[tid][2] = Ar[2]/nw;
      sA[tid][3] = Ar[3];    sA[tid][4] = Ar[4];    sA[tid][5] = Ar[5];
      sG[tid][0] = fabsf(g_G[tid*4+0]);
      sG[tid][1] = fabsf(g_G[tid*4+1]);
      sG[tid][2] = fabsf(g_G[tid*4+2]);
      sG[tid][3] = fabsf(g_G[tid*4+3]);
    }
  }
  if (tid == 0) { sg[0] = g_grav[0]; sg[1] = g_grav[1]; sg[2] = g_grav[2]; }

  float q0 = 0.f, dq0 = 0.f, qs = 0.f, dqs = 0.f;
  float accq = 0.f, accd = 0.f;
  if (r < NDOF) {
    q0  = g_state[b*14 + r];
    dq0 = g_state[b*14 + 7 + r];
    float tau = g_action[b*7 + r] * ACTION_RANGE;
    qs = q0; dqs = dq0;
    tauL[r*EP + e] = tau;
  }
  __syncthreads();

#pragma unroll 1
  for (int st = 0; st < 4; st++) {
    float bias_reg[NDOF];   // valid on lane r==7

    // ---- (A) adjoint of joint r, lanes r<7 ----
    if (r < NDOF) {
      float Ai[6];
#pragma unroll
      for (int k = 0; k < 6; k++) Ai[k] = sA[r][k];
      float Re[9], pe[3];
      exp_se3(Ai, -qs, Re, pe);
      float IRl[9];
#pragma unroll
      for (int k = 0; k < 9; k++) IRl[k] = sIR[r][k];
      float Tr9[9];
      mat3_mul(Tr9, Re, IRl);
      float Ipl[3] = {sIp[r][0], sIp[r][1], sIp[r][2]};
      float Tp[3];
      mat3_vec(Tp, Re, Ipl);
      Tp[0] += pe[0]; Tp[1] += pe[1]; Tp[2] += pe[2];
      float Bm[9];
#pragma unroll
      for (int c = 0; c < 3; c++) {
        Bm[0*3+c] = -Tp[2]*Tr9[1*3+c] + Tp[1]*Tr9[2*3+c];
        Bm[1*3+c] =  Tp[2]*Tr9[0*3+c] - Tp[0]*Tr9[2*3+c];
        Bm[2*3+c] = -Tp[1]*Tr9[0*3+c] + Tp[0]*Tr9[1*3+c];
      }
#pragma unroll
      for (int k = 0; k < 9; k++) {
        sRB[(r*18 +     k)*EP + e] = Tr9[k];
        sRB[(r*18 + 9 + k)*EP + e] = Bm[k];
      }
    }
    __syncthreads();

    // ---- (BC) fused forward+backward sweep, ALL 8 lanes ----
    // Forward carries packed chains: .x = column/V chain, .y = Vd chain.
    {
      float Phw[NDOF][3], Phv[NDOF][3];
      v2f PQw[3] = {(v2f){0.f,0.f}, (v2f){0.f,0.f}, (v2f){0.f,0.f}};
      v2f PQv[3] = {(v2f){0.f,-sg[0]}, (v2f){0.f,-sg[1]}, (v2f){0.f,-sg[2]}};
      // (.y gravity init on all lanes; only lane 7's .y is ever consumed)
#pragma unroll
      for (int i = 0; i < NDOF; i++) {
        float R[9], Bm[9];
#pragma unroll
        for (int k = 0; k < 9; k++) {
          R[k]  = sRB[(i*18 +     k)*EP + e];
          Bm[k] = sRB[(i*18 + 9 + k)*EP + e];
        }
        float dqi = __shfl(dqs, base + i, 64);
        float Aw[3] = {sA[i][0], sA[i][1], sA[i][2]};
        float Av[3] = {sA[i][3], sA[i][4], sA[i][5]};
        // packed propagation: Tw = R*PQw ; Tv = Bm*PQw + R*PQv (27 pk-FMA)
        v2f Tw[3], Tv[3];
#pragma unroll
        for (int rr = 0; rr < 3; rr++) {
          Tw[rr] = R[rr*3+0]*PQw[0] + R[rr*3+1]*PQw[1] + R[rr*3+2]*PQw[2];
          Tv[rr] = Bm[rr*3+0]*PQw[0] + Bm[rr*3+1]*PQw[1] + Bm[rr*3+2]*PQw[2]
                 + R[rr*3+0]*PQv[0] + R[rr*3+1]*PQv[1] + R[rr*3+2]*PQv[2];
        }
        // .x injection: cA * A
        float cA = (r == i) ? 1.f : ((r == 7) ? dqi : 0.f);
        float nPw[3], nPv[3];
#pragma unroll
        for (int k = 0; k < 3; k++) {
          nPw[k] = Tw[k].x + cA*Aw[k];
          nPv[k] = Tv[k].x + cA*Av[k];
        }
        // .y injection: c8 * ad(newP) A  (uses own new .x — lane-7 semantics)
        float c1[3], c2[3], c3[3];
        cross3(c1, nPw, Aw);
        cross3(c2, nPv, Aw);
        cross3(c3, nPw, Av);
        float c8 = (r == 7) ? dqi : 0.f;
#pragma unroll
        for (int k = 0; k < 3; k++) {
          PQw[k] = (v2f){nPw[k], Tw[k].y + c8*c1[k]};
          PQv[k] = (v2f){nPv[k], Tv[k].y + c8*(c2[k]+c3[k])};
        }
        if (r == 7) {
#pragma unroll
          for (int k = 0; k < 3; k++) {
            sQh[(i*6 +     k)*EP + e] = PQw[k].y;
            sQh[(i*6 + 3 + k)*EP + e] = PQv[k].y;
          }
        }
#pragma unroll
        for (int k = 0; k < 3; k++) { Phw[i][k] = nPw[k]; Phv[i][k] = nPv[k]; }
      }
      // backward (identical to R9)
      float Fw[3] = {0.f, 0.f, 0.f}, Fv[3] = {0.f, 0.f, 0.f};
#pragma unroll
      for (int i = NDOF-1; i >= 0; i--) {
        if (i < NDOF-1) {
          const int jn = i + 1;
          float R[9], Bm[9];
#pragma unroll
          for (int k = 0; k < 9; k++) {
            R[k]  = sRB[(jn*18 +     k)*EP + e];
            Bm[k] = sRB[(jn*18 + 9 + k)*EP + e];
          }
          float nw[3], nv[3], t[3];
          mat3T_vec(nw, R, Fw);
          mat3T_vec(t, Bm, Fv);
          nw[0] += t[0]; nw[1] += t[1]; nw[2] += t[2];
          mat3T_vec(nv, R, Fv);
          Fw[0] = nw[0]; Fw[1] = nw[1]; Fw[2] = nw[2];
          Fv[0] = nv[0]; Fv[1] = nv[1]; Fv[2] = nv[2];
        }
        float gx = sG[i][0], gy = sG[i][1], gz = sG[i][2], m_ = sG[i][3];
        float aw[3] = {gx*Phw[i][0], gy*Phw[i][1], gz*Phw[i][2]};
        float av[3] = {m_*Phv[i][0], m_*Phv[i][1], m_*Phv[i][2]};
        float Dw[3], Dv[3];
#pragma unroll
        for (int k = 0; k < 3; k++) {
          Dw[k] = sQh[(i*6 +     k)*EP + e];
          Dv[k] = sQh[(i*6 + 3 + k)*EP + e];
        }
        float GDw[3] = {gx*Dw[0], gy*Dw[1], gz*Dw[2]};
        float GDv[3] = {m_*Dv[0], m_*Dv[1], m_*Dv[2]};
        float x1[3], x2[3], x3[3];
        cross3(x1, Phw[i], aw);   // Vw x GVw  (lane-7 semantics)
        cross3(x2, Phv[i], av);   // Vv x GVv
        cross3(x3, Phw[i], av);   // Vw x GVv
        const bool l7 = (r == 7);
#pragma unroll
        for (int k = 0; k < 3; k++) {
          Fw[k] += l7 ? (GDw[k] + x1[k] + x2[k]) : aw[k];
          Fv[k] += l7 ? (GDv[k] + x3[k])         : av[k];
        }
        float val = Fw[0]*sA[i][0] + Fw[1]*sA[i][1] + Fw[2]*sA[i][2]
                  + Fv[0]*sA[i][3] + Fv[1]*sA[i][4] + Fv[2]*sA[i][5];
        if (r < NDOF && i >= r) MllL[(i*(i+1)/2 + r)*EP + e] = val;
        if (r == 7) bias_reg[i] = val;
      }
    }
    __syncthreads();

    // ---- (D) Cholesky solve, lane r==7 (reciprocal-cached) ----
    if (r == 7) {
      float Lm[28], invd[NDOF];
#pragma unroll
      for (int idx = 0; idx < 28; idx++) Lm[idx] = MllL[idx*EP + e];
      float y[NDOF];
#pragma unroll
      for (int i = 0; i < NDOF; i++) y[i] = tauL[i*EP + e] - bias_reg[i];
#pragma unroll
      for (int k = 0; k < NDOF; k++) {
        float d = Lm[k*(k+1)/2 + k];
#pragma unroll
        for (int m2 = 0; m2 < k; m2++) { float l = Lm[k*(k+1)/2 + m2]; d -= l*l; }
        d = sqrtf(d);
        Lm[k*(k+1)/2 + k] = d;
        float inv = 1.0f / d;
        invd[k] = inv;
#pragma unroll
        for (int i = k+1; i < NDOF; i++) {
          float s = Lm[i*(i+1)/2 + k];
#pragma unroll
          for (int m2 = 0; m2 < k; m2++) s -= Lm[i*(i+1)/2 + m2]*Lm[k*(k+1)/2 + m2];
          Lm[i*(i+1)/2 + k] = s * inv;
        }
      }
#pragma unroll
      for (int i = 0; i < NDOF; i++) {
        float s = y[i];
#pragma unroll
        for (int m2 = 0; m2 < i; m2++) s -= Lm[i*(i+1)/2 + m2]*y[m2];
        y[i] = s * invd[i];
      }
      float qac[NDOF];
#pragma unroll
      for (int i = NDOF-1; i >= 0; i--) {
        float s = y[i];
#pragma unroll
        for (int m2 = i+1; m2 < NDOF; m2++) s -= Lm[m2*(m2+1)/2 + i]*qac[m2];
        qac[i] = s * invd[i];
      }
#pragma unroll
      for (int i = 0; i < NDOF; i++) qaccL[i*EP + e] = qac[i];
    }
    __syncthreads();

    // ---- (E) RK4 stage update, lanes r<7 ----
    if (r < NDOF) {
      float a = qaccL[r*EP + e];
      float w = (st == 0 || st == 3) ? 1.0f : 2.0f;
      accq += w * dqs;
      accd += w * a;
      if (st < 3) {
        float c = (st == 2) ? HSTEP : 0.5f*HSTEP;
        qs  = q0  + c * dqs;
        dqs = dq0 + c * a;
      }
    }
  }

  const float h6 = HSTEP / 6.0f;
  if (r < NDOF) {
    float qf = wrap_pi(q0 + h6*accq);
    float v  = dq0 + h6*accd;
    float dqf = fminf(fmaxf(v, -MAX_VEL), MAX_VEL);
    qfL[r*EP + e] = qf;
    g_out_state[b*14 + r]     = qf;
    g_out_state[b*14 + 7 + r] = dqf;
  }
  __syncthreads();

  if (r == 7) {
    float Tr9[9] = {1,0,0, 0,1,0, 0,0,1};
    float Tp[3] = {0,0,0};
#pragma unroll
    for (int i = 0; i < NDOF; i++) {
      float MRl[9];
#pragma unroll
      for (int k = 0; k < 9; k++) MRl[k] = sMR[i][k];
      float Mpl[3] = {sMp[i][0], sMp[i][1], sMp[i][2]};
      float R1[9];
      mat3_mul(R1, Tr9, MRl);
      float p1[3];
      mat3_vec(p1, Tr9, Mpl);
      p1[0] += Tp[0]; p1[1] += Tp[1]; p1[2] += Tp[2];
      float Ai[6];
#pragma unroll
      for (int k = 0; k < 6; k++) Ai[k] = sA[i][k];
      float Re[9], pe[3];
      exp_se3(Ai, qfL[i*EP + e], Re, pe);
      mat3_mul(Tr9, R1, Re);
      mat3_vec(Tp, R1, pe);
      Tp[0] += p1[0]; Tp[1] += p1[1]; Tp[2] += p1[2];
    }
    float Mp7[3] = {sMp[7][0], sMp[7][1], sMp[7][2]};
    float pf[3];
    mat3_vec(pf, Tr9, Mp7);
    g_out_ee[b*2 + 0] = pf[0] + Tp[0];
    g_out_ee[b*2 + 1] = pf[1] + Tp[1];
  }
}

extern "C" void kernel_launch(void* const* d_in, const int* in_sizes, int n_in,
                              void* d_out, int out_size, void* d_ws, size_t ws_size,
                              hipStream_t stream) {
  const float* state  = (const float*)d_in[0];  // (16384,14)
  const float* action = (const float*)d_in[1];  // (16384,7)
  const float* M      = (const float*)d_in[2];  // (8,4,4)
  const float* A      = (const float*)d_in[3];  // (7,6)
  const float* G      = (const float*)d_in[4];  // (7,4)
  const float* grav   = (const float*)d_in[5];  // (3,)
  float* out_state = (float*)d_out;                       // (16384,14)
  float* out_ee    = (float*)d_out + (size_t)BATCH * 14;  // (16384,2)

  arm_rk4_kernel<<<BATCH / EPB, BLOCK, 0, stream>>>(
      state, action, M, A, G, grav, out_state, out_ee);
}

// Round 13
// 98.092 us; speedup vs baseline: 1.0911x; 1.0670x over previous
//
#include <hip/hip_runtime.h>
#include <math.h>

#define BLOCK 64
#define BATCH 16384
#define EPB 8      // elements per block: 8 lanes per element
#define EP 9       // element-dim stride for per-element LDS arrays
#define NDOF 7
#define ACTION_RANGE 50.0f
#define MAX_VEL 20.0f
#define HSTEP 0.1f

__device__ __forceinline__ void mat3_mul(float* C, const float* A, const float* B) {
#pragma unroll
  for (int r = 0; r < 3; r++) {
#pragma unroll
    for (int c = 0; c < 3; c++) {
      C[r*3+c] = A[r*3+0]*B[0*3+c] + A[r*3+1]*B[1*3+c] + A[r*3+2]*B[2*3+c];
    }
  }
}

__device__ __forceinline__ void mat3_vec(float* y, const float* A, const float* x) {
#pragma unroll
  for (int r = 0; r < 3; r++)
    y[r] = A[r*3+0]*x[0] + A[r*3+1]*x[1] + A[r*3+2]*x[2];
}

__device__ __forceinline__ void mat3T_vec(float* y, const float* A, const float* x) {
#pragma unroll
  for (int r = 0; r < 3; r++)
    y[r] = A[0*3+r]*x[0] + A[1*3+r]*x[1] + A[2*3+r]*x[2];
}

__device__ __forceinline__ void cross3(float* y, const float* a, const float* b) {
  y[0] = a[1]*b[2] - a[2]*b[1];
  y[1] = a[2]*b[0] - a[0]*b[2];
  y[2] = a[0]*b[1] - a[1]*b[0];
}

// Rodrigues-direct: for UNIT axis w, W^2 = ww^T - I, so
//   R = cI + sW + (1-c)ww^T
//   G = thI + (1-c)W + (th-s)(ww^T - I) = sI + (1-c)W + (th-s)ww^T
// Kills the 27-FMA mat3_mul(W,W) of the generic form (R13).
__device__ __forceinline__ void exp_se3(const float* A6, float th, float* R, float* p) {
  float w0 = A6[0], w1 = A6[1], w2 = A6[2];
  float s = __sinf(th);
  float c = __cosf(th);
  float omc = 1.0f - c, tms = th - s;
  float p00 = w0*w0, p01 = w0*w1, p02 = w0*w2;
  float p11 = w1*w1, p12 = w1*w2, p22 = w2*w2;
  R[0] = c + omc*p00;       R[1] = omc*p01 - s*w2;   R[2] = omc*p02 + s*w1;
  R[3] = omc*p01 + s*w2;    R[4] = c + omc*p11;      R[5] = omc*p12 - s*w0;
  R[6] = omc*p02 - s*w1;    R[7] = omc*p12 + s*w0;   R[8] = c + omc*p22;
  float G0 = s + tms*p00,    G1 = tms*p01 - omc*w2,  G2 = tms*p02 + omc*w1;
  float G3 = tms*p01 + omc*w2, G4 = s + tms*p11,     G5 = tms*p12 - omc*w0;
  float G6 = tms*p02 - omc*w1, G7 = tms*p12 + omc*w0, G8 = s + tms*p22;
  p[0] = G0*A6[3] + G1*A6[4] + G2*A6[5];
  p[1] = G3*A6[3] + G4*A6[4] + G5*A6[5];
  p[2] = G6*A6[3] + G7*A6[4] + G8*A6[5];
}

// python-style mod: a - floor(a/y)*y  (result in [0,y))
__device__ __forceinline__ float wrap_pi(float x) {
  const float PI_F   = 3.14159265358979323846f;
  const float TWO_PI = 6.28318530717958647692f;
  float a = x + PI_F;
  float r = a - floorf(a * (1.0f / TWO_PI)) * TWO_PI;
  return r - PI_F;
}

// R13 = R9 (best: 45.5us) + two cuts:
//  (a) all 7 joints' R/Bm cached in REGISTERS across the fused sweep (loaded
//      once forward, reused backward) -> -108 ds_read_b32/stage + stalls.
//      We are structurally pinned at 2 waves/SIMD (2048 waves / 1024 SIMDs),
//      so up to 256 VGPRs are free: __launch_bounds__(64,1) lifts the 128
//      tier. Live set ~210 < 256. Spill sentinel: hbm_bytes must stay ~2 MB.
//  (b) Rodrigues-direct exp_se3 (unit axis: W^2 = ww^T - I).
__global__ __launch_bounds__(BLOCK, 1) void arm_rk4_kernel(
    const float* __restrict__ g_state, const float* __restrict__ g_action,
    const float* __restrict__ g_M, const float* __restrict__ g_A,
    const float* __restrict__ g_G, const float* __restrict__ g_grav,
    float* __restrict__ g_out_state, float* __restrict__ g_out_ee)
{
  __shared__ float sMR[8][9];
  __shared__ float sMp[8][3];
  __shared__ float sIR[7][9];
  __shared__ float sIp[7][3];
  __shared__ float sA[7][6];
  __shared__ float sG[7][4];
  __shared__ float sg[3];
  __shared__ float sRB[7*18*EP];   // per joint: R[9], B[9]  (AdT = [[R,0],[B,R]])
  __shared__ float sQh[7*6*EP];    // per joint: Vd (lane-7 history)
  __shared__ float tauL[NDOF*EP];
  __shared__ float qaccL[NDOF*EP];
  __shared__ float qfL[NDOF*EP];
  __shared__ float MllL[28*EP];

  const int tid  = threadIdx.x;
  const int e    = tid >> 3;      // element slot 0..7
  const int r    = tid & 7;       // role 0..7
  const int base = tid & 0x38;    // first lane of this element group
  const int b    = blockIdx.x * EPB + e;

  if (tid < 8) {
    const float* Mi = g_M + tid*16;
    float a1[3] = {Mi[0], Mi[4], Mi[8]};
    float a2[3] = {Mi[1], Mi[5], Mi[9]};
    float p[3]  = {Mi[3], Mi[7], Mi[11]};
    float n1 = sqrtf(a1[0]*a1[0] + a1[1]*a1[1] + a1[2]*a1[2]);
    float b1[3] = {a1[0]/n1, a1[1]/n1, a1[2]/n1};
    float d = a2[0]*b1[0] + a2[1]*b1[1] + a2[2]*b1[2];
    float a2o[3] = {a2[0]-d*b1[0], a2[1]-d*b1[1], a2[2]-d*b1[2]};
    float n2 = sqrtf(a2o[0]*a2o[0] + a2o[1]*a2o[1] + a2o[2]*a2o[2]);
    float b2[3] = {a2o[0]/n2, a2o[1]/n2, a2o[2]/n2};
    float b3[3];
    cross3(b3, b1, b2);
    float R[9] = {b1[0], b2[0], b3[0],  b1[1], b2[1], b3[1],  b1[2], b2[2], b3[2]};
#pragma unroll
    for (int k = 0; k < 9; k++) sMR[tid][k] = R[k];
    sMp[tid][0] = p[0]; sMp[tid][1] = p[1]; sMp[tid][2] = p[2];
    if (tid < 7) {
#pragma unroll
      for (int rr = 0; rr < 3; rr++)
#pragma unroll
        for (int cc = 0; cc < 3; cc++) sIR[tid][rr*3+cc] = R[cc*3+rr];
#pragma unroll
      for (int rr = 0; rr < 3; rr++)
        sIp[tid][rr] = -(R[0*3+rr]*p[0] + R[1*3+rr]*p[1] + R[2*3+rr]*p[2]);
      const float* Ar = g_A + tid*6;
      float nw = sqrtf(Ar[0]*Ar[0] + Ar[1]*Ar[1] + Ar[2]*Ar[2]);
      sA[tid][0] = Ar[0]/nw; sA[tid][1] = Ar[1]/nw; sA[tid][2] = Ar[2]/nw;
      sA[tid][3] = Ar[3];    sA[tid][4] = Ar[4];    sA[tid][5] = Ar[5];
      sG[tid][0] = fabsf(g_G[tid*4+0]);
      sG[tid][1] = fabsf(g_G[tid*4+1]);
      sG[tid][2] = fabsf(g_G[tid*4+2]);
      sG[tid][3] = fabsf(g_G[tid*4+3]);
    }
  }
  if (tid == 0) { sg[0] = g_grav[0]; sg[1] = g_grav[1]; sg[2] = g_grav[2]; }

  float q0 = 0.f, dq0 = 0.f, qs = 0.f, dqs = 0.f;
  float accq = 0.f, accd = 0.f;
  if (r < NDOF) {
    q0  = g_state[b*14 + r];
    dq0 = g_state[b*14 + 7 + r];
    float tau = g_action[b*7 + r] * ACTION_RANGE;
    qs = q0; dqs = dq0;
    tauL[r*EP + e] = tau;
  }
  __syncthreads();

#pragma unroll 1
  for (int st = 0; st < 4; st++) {
    float bias_reg[NDOF];   // valid on lane r==7

    // ---- (A) adjoint of joint r, lanes r<7 ----
    if (r < NDOF) {
      float Ai[6];
#pragma unroll
      for (int k = 0; k < 6; k++) Ai[k] = sA[r][k];
      float Re[9], pe[3];
      exp_se3(Ai, -qs, Re, pe);
      float IRl[9];
#pragma unroll
      for (int k = 0; k < 9; k++) IRl[k] = sIR[r][k];
      float Tr9[9];
      mat3_mul(Tr9, Re, IRl);
      float Ipl[3] = {sIp[r][0], sIp[r][1], sIp[r][2]};
      float Tp[3];
      mat3_vec(Tp, Re, Ipl);
      Tp[0] += pe[0]; Tp[1] += pe[1]; Tp[2] += pe[2];
      float Bm[9];
#pragma unroll
      for (int c = 0; c < 3; c++) {
        Bm[0*3+c] = -Tp[2]*Tr9[1*3+c] + Tp[1]*Tr9[2*3+c];
        Bm[1*3+c] =  Tp[2]*Tr9[0*3+c] - Tp[0]*Tr9[2*3+c];
        Bm[2*3+c] = -Tp[1]*Tr9[0*3+c] + Tp[0]*Tr9[1*3+c];
      }
#pragma unroll
      for (int k = 0; k < 9; k++) {
        sRB[(r*18 +     k)*EP + e] = Tr9[k];
        sRB[(r*18 + 9 + k)*EP + e] = Bm[k];
      }
    }
    __syncthreads();

    // ---- (BC) fused forward+backward sweep, ALL 8 lanes ----
    // R/Bm loaded ONCE from LDS into registers (Rr/Br), reused backward.
    {
      float Rr[NDOF][9], Br[NDOF][9];
      float Phw[NDOF][3], Phv[NDOF][3];
      float Pw[3] = {0.f, 0.f, 0.f}, Pv[3] = {0.f, 0.f, 0.f};
      float Qw[3] = {0.f, 0.f, 0.f}, Qv[3] = {0.f, 0.f, 0.f};
      if (r == 7) { Qv[0] = -sg[0]; Qv[1] = -sg[1]; Qv[2] = -sg[2]; }
#pragma unroll
      for (int i = 0; i < NDOF; i++) {
#pragma unroll
        for (int k = 0; k < 9; k++) {
          Rr[i][k] = sRB[(i*18 +     k)*EP + e];
          Br[i][k] = sRB[(i*18 + 9 + k)*EP + e];
        }
        float dqi = __shfl(dqs, base + i, 64);
        float Aw[3] = {sA[i][0], sA[i][1], sA[i][2]};
        float Av[3] = {sA[i][3], sA[i][4], sA[i][5]};
        // P
        float Tw[3], Tv[3], t2[3];
        mat3_vec(Tw, Rr[i], Pw);
        mat3_vec(Tv, Br[i], Pw);
        mat3_vec(t2, Rr[i], Pv);
        float cA = (r == i) ? 1.f : ((r == 7) ? dqi : 0.f);
#pragma unroll
        for (int k = 0; k < 3; k++) {
          Pw[k] = Tw[k] + cA*Aw[k];
          Pv[k] = Tv[k] + t2[k] + cA*Av[k];
        }
        // Q = AdT*Q + dq_i * ad(P)A_i   (meaningful on lane 7 only)
        float Uw[3], Uv[3], u2[3];
        mat3_vec(Uw, Rr[i], Qw);
        mat3_vec(Uv, Br[i], Qw);
        mat3_vec(u2, Rr[i], Qv);
        float c1[3], c2[3], c3[3];
        cross3(c1, Pw, Aw);
        cross3(c2, Pv, Aw);
        cross3(c3, Pw, Av);
        float c8 = (r == 7) ? dqi : 0.f;
#pragma unroll
        for (int k = 0; k < 3; k++) {
          Qw[k] = Uw[k] + c8*c1[k];
          Qv[k] = Uv[k] + u2[k] + c8*(c2[k]+c3[k]);
        }
        if (r == 7) {
#pragma unroll
          for (int k = 0; k < 3; k++) {
            sQh[(i*6 +     k)*EP + e] = Qw[k];
            sQh[(i*6 + 3 + k)*EP + e] = Qv[k];
          }
        }
#pragma unroll
        for (int k = 0; k < 3; k++) { Phw[i][k] = Pw[k]; Phv[i][k] = Pv[k]; }
      }
      // backward — R/Bm from registers, no LDS
      float Fw[3] = {0.f, 0.f, 0.f}, Fv[3] = {0.f, 0.f, 0.f};
#pragma unroll
      for (int i = NDOF-1; i >= 0; i--) {
        if (i < NDOF-1) {
          const int jn = i + 1;
          float nw[3], nv[3], t[3];
          mat3T_vec(nw, Rr[jn], Fw);
          mat3T_vec(t,  Br[jn], Fv);
          nw[0] += t[0]; nw[1] += t[1]; nw[2] += t[2];
          mat3T_vec(nv, Rr[jn], Fv);
          Fw[0] = nw[0]; Fw[1] = nw[1]; Fw[2] = nw[2];
          Fv[0] = nv[0]; Fv[1] = nv[1]; Fv[2] = nv[2];
        }
        float gx = sG[i][0], gy = sG[i][1], gz = sG[i][2], m_ = sG[i][3];
        float aw[3] = {gx*Phw[i][0], gy*Phw[i][1], gz*Phw[i][2]};
        float av[3] = {m_*Phv[i][0], m_*Phv[i][1], m_*Phv[i][2]};
        float Dw[3], Dv[3];
#pragma unroll
        for (int k = 0; k < 3; k++) {
          Dw[k] = sQh[(i*6 +     k)*EP + e];
          Dv[k] = sQh[(i*6 + 3 + k)*EP + e];
        }
        float GDw[3] = {gx*Dw[0], gy*Dw[1], gz*Dw[2]};
        float GDv[3] = {m_*Dv[0], m_*Dv[1], m_*Dv[2]};
        float x1[3], x2[3], x3[3];
        cross3(x1, Phw[i], aw);   // Vw x GVw  (lane-7 semantics)
        cross3(x2, Phv[i], av);   // Vv x GVv
        cross3(x3, Phw[i], av);   // Vw x GVv
        const bool l7 = (r == 7);
#pragma unroll
        for (int k = 0; k < 3; k++) {
          Fw[k] += l7 ? (GDw[k] + x1[k] + x2[k]) : aw[k];
          Fv[k] += l7 ? (GDv[k] + x3[k])         : av[k];
        }
        float val = Fw[0]*sA[i][0] + Fw[1]*sA[i][1] + Fw[2]*sA[i][2]
                  + Fv[0]*sA[i][3] + Fv[1]*sA[i][4] + Fv[2]*sA[i][5];
        if (r < NDOF && i >= r) MllL[(i*(i+1)/2 + r)*EP + e] = val;
        if (r == 7) bias_reg[i] = val;
      }
    }
    __syncthreads();

    // ---- (D) Cholesky solve, lane r==7 (reciprocal-cached) ----
    if (r == 7) {
      float Lm[28], invd[NDOF];
#pragma unroll
      for (int idx = 0; idx < 28; idx++) Lm[idx] = MllL[idx*EP + e];
      float y[NDOF];
#pragma unroll
      for (int i = 0; i < NDOF; i++) y[i] = tauL[i*EP + e] - bias_reg[i];
#pragma unroll
      for (int k = 0; k < NDOF; k++) {
        float d = Lm[k*(k+1)/2 + k];
#pragma unroll
        for (int m2 = 0; m2 < k; m2++) { float l = Lm[k*(k+1)/2 + m2]; d -= l*l; }
        d = sqrtf(d);
        Lm[k*(k+1)/2 + k] = d;
        float inv = 1.0f / d;
        invd[k] = inv;
#pragma unroll
        for (int i = k+1; i < NDOF; i++) {
          float s = Lm[i*(i+1)/2 + k];
#pragma unroll
          for (int m2 = 0; m2 < k; m2++) s -= Lm[i*(i+1)/2 + m2]*Lm[k*(k+1)/2 + m2];
          Lm[i*(i+1)/2 + k] = s * inv;
        }
      }
#pragma unroll
      for (int i = 0; i < NDOF; i++) {
        float s = y[i];
#pragma unroll
        for (int m2 = 0; m2 < i; m2++) s -= Lm[i*(i+1)/2 + m2]*y[m2];
        y[i] = s * invd[i];
      }
      float qac[NDOF];
#pragma unroll
      for (int i = NDOF-1; i >= 0; i--) {
        float s = y[i];
#pragma unroll
        for (int m2 = i+1; m2 < NDOF; m2++) s -= Lm[m2*(m2+1)/2 + i]*qac[m2];
        qac[i] = s * invd[i];
      }
#pragma unroll
      for (int i = 0; i < NDOF; i++) qaccL[i*EP + e] = qac[i];
    }
    __syncthreads();

    // ---- (E) RK4 stage update, lanes r<7 ----
    if (r < NDOF) {
      float a = qaccL[r*EP + e];
      float w = (st == 0 || st == 3) ? 1.0f : 2.0f;
      accq += w * dqs;
      accd += w * a;
      if (st < 3) {
        float c = (st == 2) ? HSTEP : 0.5f*HSTEP;
        qs  = q0  + c * dqs;
        dqs = dq0 + c * a;
      }
    }
  }

  const float h6 = HSTEP / 6.0f;
  if (r < NDOF) {
    float qf = wrap_pi(q0 + h6*accq);
    float v  = dq0 + h6*accd;
    float dqf = fminf(fmaxf(v, -MAX_VEL), MAX_VEL);
    qfL[r*EP + e] = qf;
    g_out_state[b*14 + r]     = qf;
    g_out_state[b*14 + 7 + r] = dqf;
  }
  __syncthreads();

  if (r == 7) {
    float Tr9[9] = {1,0,0, 0,1,0, 0,0,1};
    float Tp[3] = {0,0,0};
#pragma unroll
    for (int i = 0; i < NDOF; i++) {
      float MRl[9];
#pragma unroll
      for (int k = 0; k < 9; k++) MRl[k] = sMR[i][k];
      float Mpl[3] = {sMp[i][0], sMp[i][1], sMp[i][2]};
      float R1[9];
      mat3_mul(R1, Tr9, MRl);
      float p1[3];
      mat3_vec(p1, Tr9, Mpl);
      p1[0] += Tp[0]; p1[1] += Tp[1]; p1[2] += Tp[2];
      float Ai[6];
#pragma unroll
      for (int k = 0; k < 6; k++) Ai[k] = sA[i][k];
      float Re[9], pe[3];
      exp_se3(Ai, qfL[i*EP + e], Re, pe);
      mat3_mul(Tr9, R1, Re);
      mat3_vec(Tp, R1, pe);
      Tp[0] += p1[0]; Tp[1] += p1[1]; Tp[2] += p1[2];
    }
    float Mp7[3] = {sMp[7][0], sMp[7][1], sMp[7][2]};
    float pf[3];
    mat3_vec(pf, Tr9, Mp7);
    g_out_ee[b*2 + 0] = pf[0] + Tp[0];
    g_out_ee[b*2 + 1] = pf[1] + Tp[1];
  }
}

extern "C" void kernel_launch(void* const* d_in, const int* in_sizes, int n_in,
                              void* d_out, int out_size, void* d_ws, size_t ws_size,
                              hipStream_t stream) {
  const float* state  = (const float*)d_in[0];  // (16384,14)
  const float* action = (const float*)d_in[1];  // (16384,7)
  const float* M      = (const float*)d_in[2];  // (8,4,4)
  const float* A      = (const float*)d_in[3];  // (7,6)
  const float* G      = (const float*)d_in[4];  // (7,4)
  const float* grav   = (const float*)d_in[5];  // (3,)
  float* out_state = (float*)d_out;                       // (16384,14)
  float* out_ee    = (float*)d_out + (size_t)BATCH * 14;  // (16384,2)

  arm_rk4_kernel<<<BATCH / EPB, BLOCK, 0, stream>>>(
      state, action, M, A, G, grav, out_state, out_ee);
}